// Round 3
// baseline (233.124 us; speedup 1.0000x reference)
//
#include <hip/hip_runtime.h>
#include <hip/hip_bf16.h>

// VectorQuantize: B=16, D=256, T=4096, K=1024.
//   prep    : W -> fp16 (x1024) in MFMA-direct layout [wti][ct][ks][q][n][8]
//             (one wave B-frag load = 1KB contiguous global_load_dwordx4),
//             wsq[k] = 512*||w_k||^2; zero counts/loss.
//   stageA  : scores via mfma_f32_16x16x32_f16 with B-frags straight from L2
//             (NO LDS staging, NO barriers in K-loop), rank by s - 512||e||^2,
//             per-lane top-2 -> cross-lane merge -> top-4 candidates/row.
//   stageBC : 2048 blocks x 32 rows, XLS=257 (bank-conflict-free transpose),
//             fp64 refine, winner/counts/loss, LDS w-gather -> coalesced out.
//   finalize: vq_loss + perplexity.

#define DD   256
#define KK   1024
#define TT   4096
#define BBB  16
#define NROW (BBB*TT)

typedef _Float16 half8 __attribute__((ext_vector_type(8)));
typedef float f32x4 __attribute__((ext_vector_type(4)));

__device__ __forceinline__ unsigned umaxu(unsigned a, unsigned b) { return a > b ? a : b; }
__device__ __forceinline__ unsigned uminu(unsigned a, unsigned b) { return a < b ? a : b; }

// ---------------- prep ----------------
// dst layout (halves): ((((wti*4+ct)*8+ks)*4+q)*16+n)*8 + j
//   where k = wti*64+ct*16+n, d = ks*32+q*8+j.
__global__ void prep(const float* __restrict__ w, _Float16* __restrict__ w16,
                     unsigned* __restrict__ counts, double* __restrict__ lsum,
                     float* __restrict__ wsq) {
    int gid = blockIdx.x * 256 + threadIdx.x;      // 0..32767
    int k = gid >> 5;                              // code 0..1023
    int c = gid & 31;                              // d-chunk of 8
    int wti = k >> 6, ct = (k >> 4) & 3, n = k & 15;
    int ks = c >> 2, q = c & 3;
    const float* src = w + (k << 8) + (c << 3);
    union { uint4 u; _Float16 h[8]; } pk;
#pragma unroll
    for (int j = 0; j < 8; ++j) pk.h[j] = (_Float16)(src[j] * 1024.0f);
    size_t dst = ((((size_t)(((wti << 2) + ct) << 3) + ks) * 4 + q) * 16 + n) * 8;
    *(uint4*)(w16 + dst) = pk.u;
    if (c == 0) {
        const float4* wr4 = (const float4*)(w + (k << 8));
        float s = 0.f;
#pragma unroll 8
        for (int ii = 0; ii < 64; ++ii) {
            float4 v = wr4[ii];
            s += v.x * v.x + v.y * v.y + v.z * v.z + v.w * v.w;
        }
        wsq[k] = 512.0f * s;
    }
    if (gid < KK) counts[gid] = 0u;
    if (gid == KK) *lsum = 0.0;
}

// ---------------- stage A ----------------
// 512 blocks x 256 threads (4 waves). Block owns 128 rows (one b, 128 consecutive t).
__global__ __launch_bounds__(256) void stageA(const float* __restrict__ x,
                                              const _Float16* __restrict__ w16,
                                              const float* __restrict__ wsq,
                                              uint4* __restrict__ cand) {
    __shared__ __align__(16) float wsql[KK];          // 4 KB only
    int tid = threadIdx.x, bid = blockIdx.x;
    int b = bid >> 5;
    int t0 = (bid & 31) << 7;
    const float* xbase = x + ((size_t)b << 20) + t0;

    int lane = tid & 63, wv = tid >> 6;
    int n = lane & 15, q = lane >> 4;

    ((float4*)wsql)[tid] = ((const float4*)wsq)[tid];

    // A fragments: rows wv*32 + mt*16 + n, k-elements d = ks*32 + q*8 + j
    half8 afrag[2][8];
#pragma unroll
    for (int mt = 0; mt < 2; ++mt) {
        int rl = (wv << 5) + (mt << 4) + n;
#pragma unroll
        for (int ks = 0; ks < 8; ++ks) {
            const float* p = xbase + (((size_t)((ks << 5) + (q << 3))) << 12) + rl;
            half8 f;
#pragma unroll
            for (int j = 0; j < 8; ++j) f[j] = (_Float16)p[(size_t)j << 12];
            afrag[mt][ks] = f;
        }
    }
    __syncthreads();   // wsql ready; last barrier in the kernel body

    unsigned b1[8], b2[8];
#pragma unroll
    for (int i = 0; i < 8; ++i) { b1[i] = 0u; b2[i] = 0u; }

    for (int wti = 0; wti < 16; ++wti) {
#pragma unroll
        for (int ct = 0; ct < 4; ++ct) {
            int kc = (ct << 4) + n;
            float csub = wsql[(wti << 6) + kc];
            // B-frags: contiguous 1KB per (wti,ct,ks); lane reads 16B at lane*8 halves
            const _Float16* bbase = w16 + ((size_t)(((wti << 2) + ct) << 3) << 9) + (lane << 3);
            half8 bfr[8];
#pragma unroll
            for (int ks = 0; ks < 8; ++ks)
                bfr[ks] = *(const half8*)(bbase + (ks << 9));
            f32x4 a0 = {0.f, 0.f, 0.f, 0.f};
            f32x4 a1 = {0.f, 0.f, 0.f, 0.f};
#pragma unroll
            for (int ks = 0; ks < 8; ++ks) {
                a0 = __builtin_amdgcn_mfma_f32_16x16x32_f16(afrag[0][ks], bfr[ks], a0, 0, 0, 0);
                a1 = __builtin_amdgcn_mfma_f32_16x16x32_f16(afrag[1][ks], bfr[ks], a1, 0, 0, 0);
            }
            unsigned kg = (unsigned)((wti << 6) + kc);
#pragma unroll
            for (int i = 0; i < 4; ++i) {
                float v = fmaxf(a0[i] - csub, 0.0f);
                unsigned p = (__float_as_uint(v) & 0xFFFFFC00u) | kg;
                unsigned o = b1[i];
                b2[i] = umaxu(b2[i], uminu(p, o));
                b1[i] = umaxu(o, p);
                v = fmaxf(a1[i] - csub, 0.0f);
                p = (__float_as_uint(v) & 0xFFFFFC00u) | kg;
                o = b1[4 + i];
                b2[4 + i] = umaxu(b2[4 + i], uminu(p, o));
                b1[4 + i] = umaxu(o, p);
            }
        }
    }

    // merge the 16 column-lanes' top-2 -> per-row top-4
#pragma unroll
    for (int s = 0; s < 8; ++s) {
        unsigned v0 = b1[s], v1 = b2[s], v2 = 0u, v3 = 0u;
#pragma unroll
        for (int m = 1; m <= 8; m <<= 1) {
            unsigned e0 = __shfl_xor(v0, m);
            unsigned e1 = __shfl_xor(v1, m);
            unsigned e2 = __shfl_xor(v2, m);
            unsigned e3 = __shfl_xor(v3, m);
#pragma unroll
            for (int u = 0; u < 4; ++u) {
                unsigned e = (u == 0) ? e0 : (u == 1) ? e1 : (u == 2) ? e2 : e3;
                unsigned t;
                t = umaxu(e, v0); e = uminu(e, v0); v0 = t;
                t = umaxu(e, v1); e = uminu(e, v1); v1 = t;
                t = umaxu(e, v2); e = uminu(e, v2); v2 = t;
                v3 = umaxu(e, v3);
            }
        }
        if (n == 0) {
            int row_local = (wv << 5) + ((s >> 2) << 4) + (q << 2) + (s & 3);
            cand[(bid << 7) + row_local] = make_uint4(v0, v1, v2, v3);
        }
    }
}

// ---------------- stage B+C ----------------
// 2048 blocks x 256 threads (4 waves). Block owns 32 rows (one b, 32 consecutive t).
#define XLS 257   // 257 % 32 == 1 -> conflict-free transpose
__global__ __launch_bounds__(256) void stageBC(const float* __restrict__ x,
                                               const float* __restrict__ w,
                                               const uint4* __restrict__ cand,
                                               float* __restrict__ out,
                                               unsigned* __restrict__ counts,
                                               double* __restrict__ lsum) {
    __shared__ __align__(16) float xl[32 * XLS];   // 32.9 KB; reused as w-gather
    __shared__ double disl[32][4];
    __shared__ int winner[32];
    __shared__ double ldis[32];
    int tid = threadIdx.x, bid = blockIdx.x;
    int b = bid >> 7, t0 = (bid & 127) << 5;
    int lane = tid & 63, wv = tid >> 6;

    // phase L: coalesced x tile -> LDS transposed [t][d], stride XLS
    {
        int dr = tid >> 3;                 // 0..31
        int t4 = (tid & 7) << 2;           // 0..28
        const float* xb = x + ((size_t)b << 20) + t0 + t4;
#pragma unroll
        for (int pass = 0; pass < 8; ++pass) {
            int d = (pass << 5) + dr;
            float4 v = *(const float4*)(xb + ((size_t)d << 12));
            xl[(t4 + 0) * XLS + d] = v.x;
            xl[(t4 + 1) * XLS + d] = v.y;
            xl[(t4 + 2) * XLS + d] = v.z;
            xl[(t4 + 3) * XLS + d] = v.w;
        }
    }
    __syncthreads();

    // phase R: fp64 distances; c = lane>>4 (candidate), dl = lane&15 (d chunk)
    int c = lane >> 4, dl = lane & 15;
#pragma unroll
    for (int rr = 0; rr < 8; ++rr) {
        int r = (wv << 3) + rr;
        int rowg = (b << 12) + t0 + r;
        unsigned ci = ((const unsigned*)cand)[((size_t)rowg << 2) + c] & 1023u;
        const float* wr = w + (ci << 8);
        double s = 0.0;
#pragma unroll
        for (int dd = 0; dd < 4; ++dd) {
            int d4 = (dd << 6) + (dl << 2);
            float4 xv = *(const float4*)(&xl[r * XLS + d4]);
            float4 wv4 = *(const float4*)(wr + d4);
            double e;
            e = (double)xv.x - (double)wv4.x; s = fma(e, e, s);
            e = (double)xv.y - (double)wv4.y; s = fma(e, e, s);
            e = (double)xv.z - (double)wv4.z; s = fma(e, e, s);
            e = (double)xv.w - (double)wv4.w; s = fma(e, e, s);
        }
#pragma unroll
        for (int m = 1; m <= 8; m <<= 1) s += __shfl_xor(s, m);
        if (dl == 0) disl[r][c] = s;
    }
    __syncthreads();

    // winner selection (tie -> smaller index)
    if (tid < 32) {
        int rowg = (b << 12) + t0 + tid;
        uint4 cc = cand[rowg];
        unsigned i0 = cc.x & 1023u, i1 = cc.y & 1023u, i2 = cc.z & 1023u, i3 = cc.w & 1023u;
        double dm = disl[tid][0]; unsigned ci = i0;
        double dk;
        dk = disl[tid][1]; if (dk < dm || (dk == dm && i1 < ci)) { dm = dk; ci = i1; }
        dk = disl[tid][2]; if (dk < dm || (dk == dm && i2 < ci)) { dm = dk; ci = i2; }
        dk = disl[tid][3]; if (dk < dm || (dk == dm && i3 < ci)) { dm = dk; ci = i3; }
        winner[tid] = (int)ci;
        ldis[tid] = dm;
        atomicAdd(&counts[ci], 1u);
    }
    __syncthreads();

    // gather winner w rows into LDS (reuse xl): one coalesced 1KB row per wave-instr
    float* wg = xl;
#pragma unroll
    for (int rp = 0; rp < 8; ++rp) {
        int r = (rp << 2) + wv;
        int win = winner[r];
        *(float4*)(&wg[r * XLS + (lane << 2)]) =
            *(const float4*)(w + (win << 8) + (lane << 2));
    }
    __syncthreads();

    // emit: out[b][d][t0+t] = wg[t][d], coalesced float4 along t
    {
        int dr = tid >> 3;                 // 0..31
        int t4 = (tid & 7) << 2;
        float* ob = out + ((size_t)b << 20) + t0 + t4;
#pragma unroll
        for (int pass = 0; pass < 8; ++pass) {
            int d = (pass << 5) + dr;
            float4 o;
            o.x = wg[(t4 + 0) * XLS + d];
            o.y = wg[(t4 + 1) * XLS + d];
            o.z = wg[(t4 + 2) * XLS + d];
            o.w = wg[(t4 + 3) * XLS + d];
            *(float4*)(ob + ((size_t)d << 12)) = o;
        }
    }

    // loss reduction
    __syncthreads();
    if (tid < 16) ldis[tid] += ldis[tid + 16];
    __syncthreads();
    if (tid < 8) ldis[tid] += ldis[tid + 8];
    __syncthreads();
    if (tid < 4) ldis[tid] += ldis[tid + 4];
    __syncthreads();
    if (tid < 2) ldis[tid] += ldis[tid + 2];
    __syncthreads();
    if (tid == 0) atomicAdd(lsum, ldis[0] + ldis[1]);
}

// ---------------- finalize ----------------
__global__ void finalize(const unsigned* __restrict__ counts,
                         const double* __restrict__ lsum,
                         float* __restrict__ out2) {
    __shared__ double part[256];
    int tid = threadIdx.x;
    double s = 0.0;
    for (int i = tid; i < KK; i += 256) {
        double p = (double)counts[i] / (double)NROW;
        s += p * log(p + 1e-10);
    }
    part[tid] = s;
    __syncthreads();
    for (int st = 128; st > 0; st >>= 1) {
        if (tid < st) part[tid] += part[tid + st];
        __syncthreads();
    }
    if (tid == 0) {
        out2[0] = (float)(1.25 * (*lsum) / ((double)NROW * (double)DD));
        out2[1] = (float)exp(-part[0]);
    }
}

extern "C" void kernel_launch(void* const* d_in, const int* in_sizes, int n_in,
                              void* d_out, int out_size, void* d_ws, size_t ws_size,
                              hipStream_t stream) {
    const float* x = (const float*)d_in[0];
    const float* w = (const float*)d_in[1];
    float* out = (float*)d_out;
    char* ws = (char*)d_ws;
    _Float16* w16    = (_Float16*)ws;                         // 524288 B
    uint4*    cnd    = (uint4*)(ws + 524288);                 // 1 MB
    unsigned* counts = (unsigned*)(ws + 1572864);             // 4 KB
    float*    wsq    = (float*)(ws + 1576960);                // 4 KB
    double*   lsum   = (double*)(ws + 1581056);               // 8 B

    prep<<<128, 256, 0, stream>>>(w, w16, counts, lsum, wsq);
    stageA<<<512, 256, 0, stream>>>(x, w16, wsq, (uint4*)cnd);
    stageBC<<<2048, 256, 0, stream>>>(x, w, (const uint4*)cnd, out, counts, lsum);
    finalize<<<1, 256, 0, stream>>>(counts, lsum, out + (size_t)NROW * DD);
}

// Round 4
// 216.027 us; speedup vs baseline: 1.0791x; 1.0791x over previous
//
#include <hip/hip_runtime.h>
#include <hip/hip_bf16.h>

// VectorQuantize: B=16, D=256, T=4096, K=1024.
//   prep    : W -> fp16 (x1024) in MFMA-direct layout [chunk][ks][q][n][8]
//             (chunk = wti*4+ct = 16 codes; one wave B-frag load = 1KB contiguous),
//             wsq[k] = 512*||w_k||^2; zero counts/loss.
//   stageA  : 1024 blocks x 256 thr, 64 rows/block, 16 rows (1 m-tile) per wave.
//             B-frags from L2 with explicit register double-buffer (prefetch chunk+1
//             while MFMAing chunk). Rank by s - 512||w||^2, per-lane top-2 ->
//             cross-lane merge -> top-4 candidates/row.
//   stageBC : 2048 blocks x 32 rows, XLS=257 (bank-conflict-free transpose),
//             fp64 refine, winner/counts/loss, LDS w-gather -> coalesced out.
//   finalize: vq_loss + perplexity.

#define DD   256
#define KK   1024
#define TT   4096
#define BBB  16
#define NROW (BBB*TT)

typedef _Float16 half8 __attribute__((ext_vector_type(8)));
typedef float f32x4 __attribute__((ext_vector_type(4)));

__device__ __forceinline__ unsigned umaxu(unsigned a, unsigned b) { return a > b ? a : b; }
__device__ __forceinline__ unsigned uminu(unsigned a, unsigned b) { return a < b ? a : b; }

// ---------------- prep ----------------
// dst layout (halves): (((chunk*8+ks)*4+q)*16+n)*8 + j
//   where k = chunk*16+n, d = ks*32+q*8+j.
__global__ void prep(const float* __restrict__ w, _Float16* __restrict__ w16,
                     unsigned* __restrict__ counts, double* __restrict__ lsum,
                     float* __restrict__ wsq) {
    int gid = blockIdx.x * 256 + threadIdx.x;      // 0..32767
    int k = gid >> 5;                              // code 0..1023
    int c = gid & 31;                              // d-chunk of 8
    int chunk = k >> 4, n = k & 15;
    int ks = c >> 2, q = c & 3;
    const float* src = w + (k << 8) + (c << 3);
    union { uint4 u; _Float16 h[8]; } pk;
#pragma unroll
    for (int j = 0; j < 8; ++j) pk.h[j] = (_Float16)(src[j] * 1024.0f);
    size_t dst = ((((size_t)chunk * 8 + ks) * 4 + q) * 16 + n) * 8;
    *(uint4*)(w16 + dst) = pk.u;
    if (c == 0) {
        const float4* wr4 = (const float4*)(w + (k << 8));
        float s = 0.f;
#pragma unroll 8
        for (int ii = 0; ii < 64; ++ii) {
            float4 v = wr4[ii];
            s += v.x * v.x + v.y * v.y + v.z * v.z + v.w * v.w;
        }
        wsq[k] = 512.0f * s;
    }
    if (gid < KK) counts[gid] = 0u;
    if (gid == KK) *lsum = 0.0;
}

// ---------------- stage A ----------------
// 1024 blocks x 256 threads (4 waves). Block owns 64 rows (one b, 64 consecutive t).
// Wave wv owns rows [wv*16, wv*16+16) (one m-tile).
__global__ __launch_bounds__(256) void stageA(const float* __restrict__ x,
                                              const _Float16* __restrict__ w16,
                                              const float* __restrict__ wsq,
                                              uint4* __restrict__ cand) {
    __shared__ __align__(16) float wsql[KK];          // 4 KB
    int tid = threadIdx.x, bid = blockIdx.x;
    int b = bid >> 6;
    int t0 = (bid & 63) << 6;
    const float* xbase = x + ((size_t)b << 20) + t0;

    int lane = tid & 63, wv = tid >> 6;
    int n = lane & 15, q = lane >> 4;

    ((float4*)wsql)[tid] = ((const float4*)wsq)[tid];

    // A fragment: rows wv*16 + n, k-elements d = ks*32 + q*8 + j
    half8 afrag[8];
    {
        int rl = (wv << 4) + n;
#pragma unroll
        for (int ks = 0; ks < 8; ++ks) {
            const float* p = xbase + (((size_t)((ks << 5) + (q << 3))) << 12) + rl;
            half8 f;
#pragma unroll
            for (int j = 0; j < 8; ++j) f[j] = (_Float16)p[(size_t)j << 12];
            afrag[ks] = f;
        }
    }
    __syncthreads();   // wsql ready

    unsigned b1[4], b2[4];
#pragma unroll
    for (int i = 0; i < 4; ++i) { b1[i] = 0u; b2[i] = 0u; }

    const _Float16* bbase = w16 + (lane << 3);   // chunk stride = 4096 halves (8 KB)

    half8 bA[8], bB[8];
#pragma unroll
    for (int ks = 0; ks < 8; ++ks)
        bA[ks] = *(const half8*)(bbase + (ks << 9));

    for (int ch = 0; ch < 64; ch += 2) {
        // prefetch chunk ch+1 into bB
        {
            const _Float16* nb = bbase + ((size_t)(ch + 1) << 12);
#pragma unroll
            for (int ks = 0; ks < 8; ++ks)
                bB[ks] = *(const half8*)(nb + (ks << 9));
        }
        // compute chunk ch from bA
        {
            f32x4 a = {0.f, 0.f, 0.f, 0.f};
#pragma unroll
            for (int ks = 0; ks < 8; ++ks)
                a = __builtin_amdgcn_mfma_f32_16x16x32_f16(afrag[ks], bA[ks], a, 0, 0, 0);
            unsigned kg = (unsigned)((ch << 4) + n);
            float csub = wsql[kg];
#pragma unroll
            for (int i = 0; i < 4; ++i) {
                float v = fmaxf(a[i] - csub, 0.0f);
                unsigned p = (__float_as_uint(v) & 0xFFFFFC00u) | kg;
                unsigned o = b1[i];
                b2[i] = umaxu(b2[i], uminu(p, o));
                b1[i] = umaxu(o, p);
            }
        }
        // prefetch chunk ch+2 into bA
        if (ch + 2 < 64) {
            const _Float16* nb = bbase + ((size_t)(ch + 2) << 12);
#pragma unroll
            for (int ks = 0; ks < 8; ++ks)
                bA[ks] = *(const half8*)(nb + (ks << 9));
        }
        // compute chunk ch+1 from bB
        {
            f32x4 a = {0.f, 0.f, 0.f, 0.f};
#pragma unroll
            for (int ks = 0; ks < 8; ++ks)
                a = __builtin_amdgcn_mfma_f32_16x16x32_f16(afrag[ks], bB[ks], a, 0, 0, 0);
            unsigned kg = (unsigned)(((ch + 1) << 4) + n);
            float csub = wsql[kg];
#pragma unroll
            for (int i = 0; i < 4; ++i) {
                float v = fmaxf(a[i] - csub, 0.0f);
                unsigned p = (__float_as_uint(v) & 0xFFFFFC00u) | kg;
                unsigned o = b1[i];
                b2[i] = umaxu(b2[i], uminu(p, o));
                b1[i] = umaxu(o, p);
            }
        }
    }

    // merge the 16 column-lanes' top-2 -> per-row top-4
#pragma unroll
    for (int s = 0; s < 4; ++s) {
        unsigned v0 = b1[s], v1 = b2[s], v2 = 0u, v3 = 0u;
#pragma unroll
        for (int m = 1; m <= 8; m <<= 1) {
            unsigned e0 = __shfl_xor(v0, m);
            unsigned e1 = __shfl_xor(v1, m);
            unsigned e2 = __shfl_xor(v2, m);
            unsigned e3 = __shfl_xor(v3, m);
#pragma unroll
            for (int u = 0; u < 4; ++u) {
                unsigned e = (u == 0) ? e0 : (u == 1) ? e1 : (u == 2) ? e2 : e3;
                unsigned t;
                t = umaxu(e, v0); e = uminu(e, v0); v0 = t;
                t = umaxu(e, v1); e = uminu(e, v1); v1 = t;
                t = umaxu(e, v2); e = uminu(e, v2); v2 = t;
                v3 = umaxu(e, v3);
            }
        }
        if (n == 0) {
            int row_local = (wv << 4) + (q << 2) + s;
            cand[(bid << 6) + row_local] = make_uint4(v0, v1, v2, v3);
        }
    }
}

// ---------------- stage B+C ----------------
// 2048 blocks x 256 threads (4 waves). Block owns 32 rows (one b, 32 consecutive t).
#define XLS 257   // 257 % 32 == 1 -> conflict-free transpose
__global__ __launch_bounds__(256) void stageBC(const float* __restrict__ x,
                                               const float* __restrict__ w,
                                               const uint4* __restrict__ cand,
                                               float* __restrict__ out,
                                               unsigned* __restrict__ counts,
                                               double* __restrict__ lsum) {
    __shared__ __align__(16) float xl[32 * XLS];   // 32.9 KB; reused as w-gather
    __shared__ double disl[32][4];
    __shared__ int winner[32];
    __shared__ double ldis[32];
    int tid = threadIdx.x, bid = blockIdx.x;
    int b = bid >> 7, t0 = (bid & 127) << 5;
    int lane = tid & 63, wv = tid >> 6;

    // phase L: coalesced x tile -> LDS transposed [t][d], stride XLS
    {
        int dr = tid >> 3;                 // 0..31
        int t4 = (tid & 7) << 2;           // 0..28
        const float* xb = x + ((size_t)b << 20) + t0 + t4;
#pragma unroll
        for (int pass = 0; pass < 8; ++pass) {
            int d = (pass << 5) + dr;
            float4 v = *(const float4*)(xb + ((size_t)d << 12));
            xl[(t4 + 0) * XLS + d] = v.x;
            xl[(t4 + 1) * XLS + d] = v.y;
            xl[(t4 + 2) * XLS + d] = v.z;
            xl[(t4 + 3) * XLS + d] = v.w;
        }
    }
    __syncthreads();

    // phase R: fp64 distances; c = lane>>4 (candidate), dl = lane&15 (d chunk)
    int c = lane >> 4, dl = lane & 15;
#pragma unroll
    for (int rr = 0; rr < 8; ++rr) {
        int r = (wv << 3) + rr;
        int rowg = (b << 12) + t0 + r;
        unsigned ci = ((const unsigned*)cand)[((size_t)rowg << 2) + c] & 1023u;
        const float* wr = w + (ci << 8);
        double s = 0.0;
#pragma unroll
        for (int dd = 0; dd < 4; ++dd) {
            int d4 = (dd << 6) + (dl << 2);
            float4 xv = *(const float4*)(&xl[r * XLS + d4]);
            float4 wv4 = *(const float4*)(wr + d4);
            double e;
            e = (double)xv.x - (double)wv4.x; s = fma(e, e, s);
            e = (double)xv.y - (double)wv4.y; s = fma(e, e, s);
            e = (double)xv.z - (double)wv4.z; s = fma(e, e, s);
            e = (double)xv.w - (double)wv4.w; s = fma(e, e, s);
        }
#pragma unroll
        for (int m = 1; m <= 8; m <<= 1) s += __shfl_xor(s, m);
        if (dl == 0) disl[r][c] = s;
    }
    __syncthreads();

    // winner selection (tie -> smaller index)
    if (tid < 32) {
        int rowg = (b << 12) + t0 + tid;
        uint4 cc = cand[rowg];
        unsigned i0 = cc.x & 1023u, i1 = cc.y & 1023u, i2 = cc.z & 1023u, i3 = cc.w & 1023u;
        double dm = disl[tid][0]; unsigned ci = i0;
        double dk;
        dk = disl[tid][1]; if (dk < dm || (dk == dm && i1 < ci)) { dm = dk; ci = i1; }
        dk = disl[tid][2]; if (dk < dm || (dk == dm && i2 < ci)) { dm = dk; ci = i2; }
        dk = disl[tid][3]; if (dk < dm || (dk == dm && i3 < ci)) { dm = dk; ci = i3; }
        winner[tid] = (int)ci;
        ldis[tid] = dm;
        atomicAdd(&counts[ci], 1u);
    }
    __syncthreads();

    // gather winner w rows into LDS (reuse xl): one coalesced 1KB row per wave-instr
    float* wg = xl;
#pragma unroll
    for (int rp = 0; rp < 8; ++rp) {
        int r = (rp << 2) + wv;
        int win = winner[r];
        *(float4*)(&wg[r * XLS + (lane << 2)]) =
            *(const float4*)(w + (win << 8) + (lane << 2));
    }
    __syncthreads();

    // emit: out[b][d][t0+t] = wg[t][d], coalesced float4 along t
    {
        int dr = tid >> 3;                 // 0..31
        int t4 = (tid & 7) << 2;
        float* ob = out + ((size_t)b << 20) + t0 + t4;
#pragma unroll
        for (int pass = 0; pass < 8; ++pass) {
            int d = (pass << 5) + dr;
            float4 o;
            o.x = wg[(t4 + 0) * XLS + d];
            o.y = wg[(t4 + 1) * XLS + d];
            o.z = wg[(t4 + 2) * XLS + d];
            o.w = wg[(t4 + 3) * XLS + d];
            *(float4*)(ob + ((size_t)d << 12)) = o;
        }
    }

    // loss reduction
    __syncthreads();
    if (tid < 16) ldis[tid] += ldis[tid + 16];
    __syncthreads();
    if (tid < 8) ldis[tid] += ldis[tid + 8];
    __syncthreads();
    if (tid < 4) ldis[tid] += ldis[tid + 4];
    __syncthreads();
    if (tid < 2) ldis[tid] += ldis[tid + 2];
    __syncthreads();
    if (tid == 0) atomicAdd(lsum, ldis[0] + ldis[1]);
}

// ---------------- finalize ----------------
__global__ void finalize(const unsigned* __restrict__ counts,
                         const double* __restrict__ lsum,
                         float* __restrict__ out2) {
    __shared__ double part[256];
    int tid = threadIdx.x;
    double s = 0.0;
    for (int i = tid; i < KK; i += 256) {
        double p = (double)counts[i] / (double)NROW;
        s += p * log(p + 1e-10);
    }
    part[tid] = s;
    __syncthreads();
    for (int st = 128; st > 0; st >>= 1) {
        if (tid < st) part[tid] += part[tid + st];
        __syncthreads();
    }
    if (tid == 0) {
        out2[0] = (float)(1.25 * (*lsum) / ((double)NROW * (double)DD));
        out2[1] = (float)exp(-part[0]);
    }
}

extern "C" void kernel_launch(void* const* d_in, const int* in_sizes, int n_in,
                              void* d_out, int out_size, void* d_ws, size_t ws_size,
                              hipStream_t stream) {
    const float* x = (const float*)d_in[0];
    const float* w = (const float*)d_in[1];
    float* out = (float*)d_out;
    char* ws = (char*)d_ws;
    _Float16* w16    = (_Float16*)ws;                         // 524288 B
    uint4*    cnd    = (uint4*)(ws + 524288);                 // 1 MB
    unsigned* counts = (unsigned*)(ws + 1572864);             // 4 KB
    float*    wsq    = (float*)(ws + 1576960);                // 4 KB
    double*   lsum   = (double*)(ws + 1581056);               // 8 B

    prep<<<128, 256, 0, stream>>>(w, w16, counts, lsum, wsq);
    stageA<<<1024, 256, 0, stream>>>(x, w16, wsq, (uint4*)cnd);
    stageBC<<<2048, 256, 0, stream>>>(x, w, (const uint4*)cnd, out, counts, lsum);
    finalize<<<1, 256, 0, stream>>>(counts, lsum, out + (size_t)NROW * DD);
}

// Round 5
// 203.065 us; speedup vs baseline: 1.1480x; 1.0638x over previous
//
#include <hip/hip_runtime.h>
#include <hip/hip_bf16.h>

// VectorQuantize: B=16, D=256, T=4096, K=1024.
//   prep    : W -> fp16 (x1024) in chunk-linear MFMA layout [chunk][ks][q][n][8]
//             (chunk = 16 codes = 8 KB contiguous), wsq[k]=512*||w_k||^2.
//   stageA  : 512 blocks x 256 thr (4 waves), 32 rows/wave. B chunks staged through
//             2x8KB LDS double-buffer (1 barrier/chunk, VGPR-prefetch of chunk+1),
//             shared by all 4 waves => L2 B-traffic 256 MB total (was 2 GB).
//             mfma_f32_16x16x32_f16, rank by s-512||w||^2, per-lane top-2 ->
//             cross-lane merge -> top-4 candidates/row.
//   stageBC : 2048 blocks x 32 rows, XLS=257, fp64 refine, winner/counts/loss,
//             LDS w-gather -> coalesced out.
//   finalize: vq_loss + perplexity.

#define DD   256
#define KK   1024
#define TT   4096
#define BBB  16
#define NROW (BBB*TT)

typedef _Float16 half8 __attribute__((ext_vector_type(8)));
typedef float f32x4 __attribute__((ext_vector_type(4)));

__device__ __forceinline__ unsigned umaxu(unsigned a, unsigned b) { return a > b ? a : b; }
__device__ __forceinline__ unsigned uminu(unsigned a, unsigned b) { return a < b ? a : b; }

// ---------------- prep ----------------
// dst layout (halves): (((chunk*8+ks)*4+q)*16+n)*8 + j ; k = chunk*16+n, d = ks*32+q*8+j.
__global__ void prep(const float* __restrict__ w, _Float16* __restrict__ w16,
                     unsigned* __restrict__ counts, double* __restrict__ lsum,
                     float* __restrict__ wsq) {
    int gid = blockIdx.x * 256 + threadIdx.x;      // 0..32767
    int k = gid >> 5;                              // code 0..1023
    int c = gid & 31;                              // d-chunk of 8
    int chunk = k >> 4, n = k & 15;
    int ks = c >> 2, q = c & 3;
    const float* src = w + (k << 8) + (c << 3);
    union { uint4 u; _Float16 h[8]; } pk;
#pragma unroll
    for (int j = 0; j < 8; ++j) pk.h[j] = (_Float16)(src[j] * 1024.0f);
    size_t dst = ((((size_t)chunk * 8 + ks) * 4 + q) * 16 + n) * 8;
    *(uint4*)(w16 + dst) = pk.u;
    if (c == 0) {
        const float4* wr4 = (const float4*)(w + (k << 8));
        float s = 0.f;
#pragma unroll 8
        for (int ii = 0; ii < 64; ++ii) {
            float4 v = wr4[ii];
            s += v.x * v.x + v.y * v.y + v.z * v.z + v.w * v.w;
        }
        wsq[k] = 512.0f * s;
    }
    if (gid < KK) counts[gid] = 0u;
    if (gid == KK) *lsum = 0.0;
}

// ---------------- stage A ----------------
// 512 blocks x 256 threads (4 waves). Block owns 128 rows (one b, 128 consecutive t).
// Wave wv owns rows [wv*32, wv*32+32) = two 16-row m-tiles.
__global__ __launch_bounds__(256) void stageA(const float* __restrict__ x,
                                              const _Float16* __restrict__ w16,
                                              const float* __restrict__ wsq,
                                              uint4* __restrict__ cand) {
    __shared__ __align__(16) float wsql[KK];              // 4 KB
    __shared__ __align__(16) _Float16 bbuf[2][4096];      // 2 x 8 KB double buffer
    int tid = threadIdx.x, bid = blockIdx.x;
    int b = bid >> 5;
    int t0 = (bid & 31) << 7;
    const float* xbase = x + ((size_t)b << 20) + t0;

    int lane = tid & 63, wv = tid >> 6;
    int n = lane & 15, q = lane >> 4;

    ((float4*)wsql)[tid] = ((const float4*)wsq)[tid];

    // A fragments (register-resident, whole K=256): rows wv*32+mt*16+n, d = ks*32+q*8+j
    half8 afrag[2][8];
#pragma unroll
    for (int mt = 0; mt < 2; ++mt) {
        int rl = (wv << 5) + (mt << 4) + n;
#pragma unroll
        for (int ks = 0; ks < 8; ++ks) {
            const float* p = xbase + (((size_t)((ks << 5) + (q << 3))) << 12) + rl;
            half8 f;
#pragma unroll
            for (int j = 0; j < 8; ++j) f[j] = (_Float16)p[(size_t)j << 12];
            afrag[mt][ks] = f;
        }
    }

    // stage chunk 0 into bbuf[0]
    const uint4* wsrc = (const uint4*)w16;   // chunk ch at uint4 index ch*512
    {
        uint4 p0 = wsrc[tid];
        uint4 p1 = wsrc[tid + 256];
        ((uint4*)bbuf[0])[tid] = p0;
        ((uint4*)bbuf[0])[tid + 256] = p1;
    }
    __syncthreads();

    unsigned b1[8], b2[8];
#pragma unroll
    for (int i = 0; i < 8; ++i) { b1[i] = 0u; b2[i] = 0u; }

    for (int ch = 0; ch < 64; ++ch) {
        // prefetch chunk ch+1 into VGPRs
        uint4 p0, p1;
        if (ch + 1 < 64) {
            p0 = wsrc[((ch + 1) << 9) + tid];
            p1 = wsrc[((ch + 1) << 9) + tid + 256];
        }
        // compute chunk ch from bbuf[ch&1]
        {
            const _Float16* bb = bbuf[ch & 1];
            half8 bfr[8];
#pragma unroll
            for (int ks = 0; ks < 8; ++ks)
                bfr[ks] = *(const half8*)(bb + (ks << 9) + (lane << 3));
            f32x4 a0 = {0.f, 0.f, 0.f, 0.f};
            f32x4 a1 = {0.f, 0.f, 0.f, 0.f};
#pragma unroll
            for (int ks = 0; ks < 8; ++ks) {
                a0 = __builtin_amdgcn_mfma_f32_16x16x32_f16(afrag[0][ks], bfr[ks], a0, 0, 0, 0);
                a1 = __builtin_amdgcn_mfma_f32_16x16x32_f16(afrag[1][ks], bfr[ks], a1, 0, 0, 0);
            }
            unsigned kg = (unsigned)((ch << 4) + n);
            float csub = wsql[kg];
#pragma unroll
            for (int i = 0; i < 4; ++i) {
                float v = fmaxf(a0[i] - csub, 0.0f);
                unsigned p = (__float_as_uint(v) & 0xFFFFFC00u) | kg;
                unsigned o = b1[i];
                b2[i] = umaxu(b2[i], uminu(p, o));
                b1[i] = umaxu(o, p);
                v = fmaxf(a1[i] - csub, 0.0f);
                p = (__float_as_uint(v) & 0xFFFFFC00u) | kg;
                o = b1[4 + i];
                b2[4 + i] = umaxu(b2[4 + i], uminu(p, o));
                b1[4 + i] = umaxu(o, p);
            }
        }
        // write prefetched chunk into the other buffer (free this iteration)
        if (ch + 1 < 64) {
            _Float16* db = bbuf[(ch + 1) & 1];
            ((uint4*)db)[tid] = p0;
            ((uint4*)db)[tid + 256] = p1;
        }
        __syncthreads();
    }

    // merge the 16 column-lanes' top-2 -> per-row top-4
#pragma unroll
    for (int s = 0; s < 8; ++s) {
        unsigned v0 = b1[s], v1 = b2[s], v2 = 0u, v3 = 0u;
#pragma unroll
        for (int m = 1; m <= 8; m <<= 1) {
            unsigned e0 = __shfl_xor(v0, m);
            unsigned e1 = __shfl_xor(v1, m);
            unsigned e2 = __shfl_xor(v2, m);
            unsigned e3 = __shfl_xor(v3, m);
#pragma unroll
            for (int u = 0; u < 4; ++u) {
                unsigned e = (u == 0) ? e0 : (u == 1) ? e1 : (u == 2) ? e2 : e3;
                unsigned t;
                t = umaxu(e, v0); e = uminu(e, v0); v0 = t;
                t = umaxu(e, v1); e = uminu(e, v1); v1 = t;
                t = umaxu(e, v2); e = uminu(e, v2); v2 = t;
                v3 = umaxu(e, v3);
            }
        }
        if (n == 0) {
            int row_local = (wv << 5) + ((s >> 2) << 4) + (q << 2) + (s & 3);
            cand[(bid << 7) + row_local] = make_uint4(v0, v1, v2, v3);
        }
    }
}

// ---------------- stage B+C ----------------
// 2048 blocks x 256 threads (4 waves). Block owns 32 rows (one b, 32 consecutive t).
#define XLS 257   // 257 % 32 == 1 -> conflict-free transpose
__global__ __launch_bounds__(256) void stageBC(const float* __restrict__ x,
                                               const float* __restrict__ w,
                                               const uint4* __restrict__ cand,
                                               float* __restrict__ out,
                                               unsigned* __restrict__ counts,
                                               double* __restrict__ lsum) {
    __shared__ __align__(16) float xl[32 * XLS];   // 32.9 KB; reused as w-gather
    __shared__ double disl[32][4];
    __shared__ int winner[32];
    __shared__ double ldis[32];
    int tid = threadIdx.x, bid = blockIdx.x;
    int b = bid >> 7, t0 = (bid & 127) << 5;
    int lane = tid & 63, wv = tid >> 6;

    // phase L: coalesced x tile -> LDS transposed [t][d], stride XLS
    {
        int dr = tid >> 3;                 // 0..31
        int t4 = (tid & 7) << 2;           // 0..28
        const float* xb = x + ((size_t)b << 20) + t0 + t4;
#pragma unroll
        for (int pass = 0; pass < 8; ++pass) {
            int d = (pass << 5) + dr;
            float4 v = *(const float4*)(xb + ((size_t)d << 12));
            xl[(t4 + 0) * XLS + d] = v.x;
            xl[(t4 + 1) * XLS + d] = v.y;
            xl[(t4 + 2) * XLS + d] = v.z;
            xl[(t4 + 3) * XLS + d] = v.w;
        }
    }
    __syncthreads();

    // phase R: fp64 distances; c = lane>>4 (candidate), dl = lane&15 (d chunk)
    int c = lane >> 4, dl = lane & 15;
#pragma unroll
    for (int rr = 0; rr < 8; ++rr) {
        int r = (wv << 3) + rr;
        int rowg = (b << 12) + t0 + r;
        unsigned ci = ((const unsigned*)cand)[((size_t)rowg << 2) + c] & 1023u;
        const float* wr = w + (ci << 8);
        double s = 0.0;
#pragma unroll
        for (int dd = 0; dd < 4; ++dd) {
            int d4 = (dd << 6) + (dl << 2);
            float4 xv = *(const float4*)(&xl[r * XLS + d4]);
            float4 wv4 = *(const float4*)(wr + d4);
            double e;
            e = (double)xv.x - (double)wv4.x; s = fma(e, e, s);
            e = (double)xv.y - (double)wv4.y; s = fma(e, e, s);
            e = (double)xv.z - (double)wv4.z; s = fma(e, e, s);
            e = (double)xv.w - (double)wv4.w; s = fma(e, e, s);
        }
#pragma unroll
        for (int m = 1; m <= 8; m <<= 1) s += __shfl_xor(s, m);
        if (dl == 0) disl[r][c] = s;
    }
    __syncthreads();

    // winner selection (tie -> smaller index)
    if (tid < 32) {
        int rowg = (b << 12) + t0 + tid;
        uint4 cc = cand[rowg];
        unsigned i0 = cc.x & 1023u, i1 = cc.y & 1023u, i2 = cc.z & 1023u, i3 = cc.w & 1023u;
        double dm = disl[tid][0]; unsigned ci = i0;
        double dk;
        dk = disl[tid][1]; if (dk < dm || (dk == dm && i1 < ci)) { dm = dk; ci = i1; }
        dk = disl[tid][2]; if (dk < dm || (dk == dm && i2 < ci)) { dm = dk; ci = i2; }
        dk = disl[tid][3]; if (dk < dm || (dk == dm && i3 < ci)) { dm = dk; ci = i3; }
        winner[tid] = (int)ci;
        ldis[tid] = dm;
        atomicAdd(&counts[ci], 1u);
    }
    __syncthreads();

    // gather winner w rows into LDS (reuse xl): one coalesced 1KB row per wave-instr
    float* wg = xl;
#pragma unroll
    for (int rp = 0; rp < 8; ++rp) {
        int r = (rp << 2) + wv;
        int win = winner[r];
        *(float4*)(&wg[r * XLS + (lane << 2)]) =
            *(const float4*)(w + (win << 8) + (lane << 2));
    }
    __syncthreads();

    // emit: out[b][d][t0+t] = wg[t][d], coalesced float4 along t
    {
        int dr = tid >> 3;                 // 0..31
        int t4 = (tid & 7) << 2;
        float* ob = out + ((size_t)b << 20) + t0 + t4;
#pragma unroll
        for (int pass = 0; pass < 8; ++pass) {
            int d = (pass << 5) + dr;
            float4 o;
            o.x = wg[(t4 + 0) * XLS + d];
            o.y = wg[(t4 + 1) * XLS + d];
            o.z = wg[(t4 + 2) * XLS + d];
            o.w = wg[(t4 + 3) * XLS + d];
            *(float4*)(ob + ((size_t)d << 12)) = o;
        }
    }

    // loss reduction
    __syncthreads();
    if (tid < 16) ldis[tid] += ldis[tid + 16];
    __syncthreads();
    if (tid < 8) ldis[tid] += ldis[tid + 8];
    __syncthreads();
    if (tid < 4) ldis[tid] += ldis[tid + 4];
    __syncthreads();
    if (tid < 2) ldis[tid] += ldis[tid + 2];
    __syncthreads();
    if (tid == 0) atomicAdd(lsum, ldis[0] + ldis[1]);
}

// ---------------- finalize ----------------
__global__ void finalize(const unsigned* __restrict__ counts,
                         const double* __restrict__ lsum,
                         float* __restrict__ out2) {
    __shared__ double part[256];
    int tid = threadIdx.x;
    double s = 0.0;
    for (int i = tid; i < KK; i += 256) {
        double p = (double)counts[i] / (double)NROW;
        s += p * log(p + 1e-10);
    }
    part[tid] = s;
    __syncthreads();
    for (int st = 128; st > 0; st >>= 1) {
        if (tid < st) part[tid] += part[tid + st];
        __syncthreads();
    }
    if (tid == 0) {
        out2[0] = (float)(1.25 * (*lsum) / ((double)NROW * (double)DD));
        out2[1] = (float)exp(-part[0]);
    }
}

extern "C" void kernel_launch(void* const* d_in, const int* in_sizes, int n_in,
                              void* d_out, int out_size, void* d_ws, size_t ws_size,
                              hipStream_t stream) {
    const float* x = (const float*)d_in[0];
    const float* w = (const float*)d_in[1];
    float* out = (float*)d_out;
    char* ws = (char*)d_ws;
    _Float16* w16    = (_Float16*)ws;                         // 524288 B
    uint4*    cnd    = (uint4*)(ws + 524288);                 // 1 MB
    unsigned* counts = (unsigned*)(ws + 1572864);             // 4 KB
    float*    wsq    = (float*)(ws + 1576960);                // 4 KB
    double*   lsum   = (double*)(ws + 1581056);               // 8 B

    prep<<<128, 256, 0, stream>>>(w, w16, counts, lsum, wsq);
    stageA<<<512, 256, 0, stream>>>(x, w16, wsq, (uint4*)cnd);
    stageBC<<<2048, 256, 0, stream>>>(x, w, (const uint4*)cnd, out, counts, lsum);
    finalize<<<1, 256, 0, stream>>>(counts, lsum, out + (size_t)NROW * DD);
}